// Round 10
// baseline (181.723 us; speedup 1.0000x reference)
//
#include <hip/hip_runtime.h>
#include <math.h>

#define EPS_F 1.1754943508222875e-38f

typedef __attribute__((ext_vector_type(8))) _Float16 half8;
typedef __attribute__((ext_vector_type(4))) float f32x4;
typedef __attribute__((ext_vector_type(8))) unsigned short ushort8;

__device__ __forceinline__ unsigned short f2h(float f) {
  _Float16 h = (_Float16)f;
  return __builtin_bit_cast(unsigned short, h);
}
__device__ __forceinline__ float h2f(unsigned short u) {
  return (float)__builtin_bit_cast(_Float16, u);
}

// async global->LDS, 16B/lane; LDS dest = wave-uniform base (+ lane*16 by HW)
__device__ __forceinline__ void gload16(const void* g, void* l) {
  __builtin_amdgcn_global_load_lds(
      (const __attribute__((address_space(1))) void*)g,
      (__attribute__((address_space(3))) void*)l, 16, 0, 0);
}

// ---------------- prep: x transpose + f16 convert ----------------
__global__ __launch_bounds__(256) void k_prep_x(const float* __restrict__ in,
                                                unsigned short* __restrict__ x) {
  __shared__ float t[32][33];
  int c0 = blockIdx.x * 32, p0 = blockIdx.y * 32, b = blockIdx.z;
  int tx = threadIdx.x & 31, ty = threadIdx.x >> 5;
#pragma unroll
  for (int i = ty; i < 32; i += 8)
    t[i][tx] = in[(b * 256 + p0 + i) * 512 + c0 + tx];
  __syncthreads();
#pragma unroll
  for (int i = ty; i < 32; i += 8)
    x[(b * 512 + c0 + i) * 256 + p0 + tx] = f2h(t[tx][i]);
}

// ---------------- prep weights: wd=(Wq-Wk)/sigma (f16), woh (f16), bdr, L1 partials ----------------
__global__ __launch_bounds__(256) void k_prep_w(
    const float* __restrict__ Wq, const float* __restrict__ Wk,
    const float* __restrict__ Wv, const float* __restrict__ Wo,
    const float* __restrict__ bq, const float* __restrict__ bk,
    const float* __restrict__ sigma,
    unsigned short* __restrict__ wd, unsigned short* __restrict__ woh,
    float* __restrict__ bdr, float* __restrict__ pbk, float* __restrict__ pbv) {
  __shared__ float r1[4], r2[4];
  int gid = blockIdx.x * 256 + threadIdx.x;
  int i4 = gid * 4;
  int rm = i4 >> 8, p = i4 & 255, m = rm & 255;
  const float4 wk = *(const float4*)(Wk + i4);
  const float4 wv = *(const float4*)(Wv + i4);
  const float4 wq = *(const float4*)(Wq + m * 256 + p);
  float rs = 1.0f / (sigma[rm] + EPS_F);
  ushort4 d;
  d.x = f2h((wq.x - wk.x) * rs); d.y = f2h((wq.y - wk.y) * rs);
  d.z = f2h((wq.z - wk.z) * rs); d.w = f2h((wq.w - wk.w) * rs);
  *(ushort4*)(wd + i4) = d;
  float ak = fabsf(wk.x) + fabsf(wk.y) + fabsf(wk.z) + fabsf(wk.w);
  float av = fabsf(wv.x) + fabsf(wv.y) + fabsf(wv.z) + fabsf(wv.w);
  if (p == 0) bdr[rm] = (bq[m] - bk[rm]) * rs;
  if (gid < 65536) woh[gid] = f2h(Wo[gid]);
  int lane = threadIdx.x & 63, w = threadIdx.x >> 6;
#pragma unroll
  for (int dlt = 1; dlt < 64; dlt <<= 1) {
    ak += __shfl_xor(ak, dlt);
    av += __shfl_xor(av, dlt);
  }
  if (lane == 0) { r1[w] = ak; r2[w] = av; }
  __syncthreads();
  if (threadIdx.x == 0) {
    pbk[blockIdx.x] = r1[0] + r1[1] + r1[2] + r1[3];
    pbv[blockIdx.x] = r2[0] + r2[1] + r2[2] + r2[3];
  }
}

// ---------------- transpose Wv -> wvT[r][p][m] f16 ----------------
__global__ __launch_bounds__(256) void k_tv(const float* __restrict__ Wv,
                                            unsigned short* __restrict__ wvT) {
  __shared__ float t[32][33];
  int p0 = blockIdx.x * 32, m0 = blockIdx.y * 32, r = blockIdx.z;
  int tx = threadIdx.x & 31, ty = threadIdx.x >> 5;
#pragma unroll
  for (int i = ty; i < 32; i += 8)
    t[i][tx] = Wv[(size_t)(r * 256 + m0 + i) * 256 + p0 + tx];
  __syncthreads();
#pragma unroll
  for (int i = ty; i < 32; i += 8)
    wvT[(size_t)r * 65536 + (p0 + i) * 256 + m0 + tx] = f2h(t[tx][i]);
}

// ---------------- loss: ||Wq@Wo - I||^2 per-block partial ----------------
__global__ __launch_bounds__(256) void k_wqwo(const float* __restrict__ Wq,
                                              const float* __restrict__ Wo,
                                              float* __restrict__ pbw) {
  __shared__ float wq[256];
  __shared__ float red[4];
  int i = blockIdx.x, j = threadIdx.x;
  wq[j] = Wq[i * 256 + j];
  __syncthreads();
  float s = 0.f;
#pragma unroll 8
  for (int p = 0; p < 256; ++p) s = fmaf(wq[p], Wo[p * 256 + j], s);
  float d = s - (i == j ? 1.0f : 0.0f);
  float x = d * d;
#pragma unroll
  for (int dd = 1; dd < 64; dd <<= 1) x += __shfl_xor(x, dd);
  if ((j & 63) == 0) red[j >> 6] = x;
  __syncthreads();
  if (j == 0) pbw[blockIdx.x] = red[0] + red[1] + red[2] + red[3];
}

// ============ k_gw: G_r[p'][p] = sum_m Wo[p'][m]*Wv_r[m][p] ============
// grid (2 pl, 2 ph, 64 r), 256 thr (4 waves 2x2), tile 128x128, BK=64, K=256
__global__ __launch_bounds__(256) void k_gw(const unsigned short* __restrict__ woh,
                                            const unsigned short* __restrict__ wvT,
                                            unsigned short* __restrict__ G) {
  __shared__ unsigned short As[128 * 64];
  __shared__ unsigned short Bs[128 * 64];
  const int tid = threadIdx.x, w = tid >> 6, lane = tid & 63;
  const int wr = w >> 1, wc = w & 1, cl = lane & 15, kg = lane >> 4;
  const int pl = blockIdx.x, ph = blockIdx.y, r = blockIdx.z;

  f32x4 acc[4][4];
#pragma unroll
  for (int i = 0; i < 4; ++i)
#pragma unroll
    for (int j = 0; j < 4; ++j) acc[i][j] = (f32x4){0.f, 0.f, 0.f, 0.f};

  for (int t = 0; t < 4; ++t) {
    const int kc = t * 64;
    __syncthreads();
#pragma unroll
    for (int j = 0; j < 4; ++j) {
      int s = w * 4 + j;
      int ch = s * 64 + lane;
      int row = ch >> 3, c = ch & 7;
      gload16(woh + (ph * 128 + row) * 256 + kc + ((c ^ (row & 7)) << 3),
              As + s * 512);
      gload16(wvT + (size_t)r * 65536 + (pl * 128 + row) * 256 + kc +
                  ((c ^ (row & 7)) << 3),
              Bs + s * 512);
    }
    __syncthreads();
#pragma unroll
    for (int kk = 0; kk < 2; ++kk) {
      half8 a[4], b[4];
      int g = kk * 4 + kg;
#pragma unroll
      for (int i = 0; i < 4; ++i) {
        int row = wr * 64 + i * 16 + cl;
        a[i] = *(const half8*)(As + row * 64 + ((g ^ (row & 7)) << 3));
      }
#pragma unroll
      for (int j = 0; j < 4; ++j) {
        int n = wc * 64 + j * 16 + cl;
        b[j] = *(const half8*)(Bs + n * 64 + ((g ^ (n & 7)) << 3));
      }
#pragma unroll
      for (int i = 0; i < 4; ++i)
#pragma unroll
        for (int j = 0; j < 4; ++j)
          acc[i][j] = __builtin_amdgcn_mfma_f32_16x16x32_f16(a[i], b[j], acc[i][j], 0, 0, 0);
    }
  }
#pragma unroll
  for (int i = 0; i < 4; ++i)
#pragma unroll
    for (int q = 0; q < 4; ++q) {
      int pr = ph * 128 + wr * 64 + i * 16 + kg * 4 + q;
#pragma unroll
      for (int j = 0; j < 4; ++j) {
        int pc = pl * 128 + wc * 64 + j * 16 + cl;
        G[(size_t)r * 65536 + pr * 256 + pc] = f2h(acc[i][j][q]);
      }
    }
}

// ---------------- hv[r][p'] = sum_m Wo[p'][m]*bv[r][m] ----------------
__global__ __launch_bounds__(256) void k_hv(const unsigned short* __restrict__ woh,
                                            const float* __restrict__ bv,
                                            float* __restrict__ hv) {
  __shared__ float bvl[256];
  int r = blockIdx.x, t = threadIdx.x;
  bvl[t] = bv[r * 256 + t];
  __syncthreads();
  float s = 0.f;
#pragma unroll 8
  for (int c8 = 0; c8 < 32; ++c8) {
    ushort8 wv8 = *(const ushort8*)(woh + t * 256 + c8 * 8);
#pragma unroll
    for (int e = 0; e < 8; ++e) s = fmaf(h2f(wv8[e]), bvl[c8 * 8 + e], s);
  }
  hv[r * 256 + t] = s;
}

// ============ k_fire (m97 BK=64): per r, C = x@wd_r^T, atomic square-reduce ============
// grid (2 mh, 32 bc, 64 r), 256 thr, tile 128bc x 128m, BK=64, K=256
__global__ __launch_bounds__(256) void k_fire(
    const unsigned short* __restrict__ xh, const unsigned short* __restrict__ wd,
    const float* __restrict__ bdr, float* __restrict__ fire_p) {
  __shared__ unsigned short As[128 * 64];
  __shared__ unsigned short Bs[128 * 64];
  __shared__ float red[128][2];
  const int tid = threadIdx.x, w = tid >> 6, lane = tid & 63;
  const int wr = w >> 1, wc = w & 1, cl = lane & 15, kg = lane >> 4;
  const int mh = blockIdx.x, bc0 = blockIdx.y * 128, r = blockIdx.z;

  float bdrv[4];
#pragma unroll
  for (int j = 0; j < 4; ++j)
    bdrv[j] = bdr[r * 256 + mh * 128 + wc * 64 + j * 16 + cl];

  f32x4 acc[4][4];
#pragma unroll
  for (int i = 0; i < 4; ++i)
#pragma unroll
    for (int j = 0; j < 4; ++j) acc[i][j] = (f32x4){0.f, 0.f, 0.f, 0.f};

  for (int t = 0; t < 4; ++t) {
    const int kc = t * 64;
    __syncthreads();
#pragma unroll
    for (int j = 0; j < 4; ++j) {
      int s = w * 4 + j;
      int ch = s * 64 + lane;
      int row = ch >> 3, c = ch & 7;
      gload16(xh + (size_t)(bc0 + row) * 256 + kc + ((c ^ (row & 7)) << 3),
              As + s * 512);
      gload16(wd + (size_t)r * 65536 + (mh * 128 + row) * 256 + kc +
                  ((c ^ (row & 7)) << 3),
              Bs + s * 512);
    }
    __syncthreads();
#pragma unroll
    for (int kk = 0; kk < 2; ++kk) {
      half8 a[4], b[4];
      int g = kk * 4 + kg;
#pragma unroll
      for (int i = 0; i < 4; ++i) {
        int row = wr * 64 + i * 16 + cl;
        a[i] = *(const half8*)(As + row * 64 + ((g ^ (row & 7)) << 3));
      }
#pragma unroll
      for (int j = 0; j < 4; ++j) {
        int n = wc * 64 + j * 16 + cl;
        b[j] = *(const half8*)(Bs + n * 64 + ((g ^ (n & 7)) << 3));
      }
#pragma unroll
      for (int i = 0; i < 4; ++i)
#pragma unroll
        for (int j = 0; j < 4; ++j)
          acc[i][j] = __builtin_amdgcn_mfma_f32_16x16x32_f16(a[i], b[j], acc[i][j], 0, 0, 0);
    }
  }
  float rowsum[4][4];
#pragma unroll
  for (int i = 0; i < 4; ++i)
#pragma unroll
    for (int q = 0; q < 4; ++q) {
      float s2 = 0.f;
#pragma unroll
      for (int j = 0; j < 4; ++j) {
        float t2 = acc[i][j][q] + bdrv[j];
        s2 += t2 * t2;
      }
      rowsum[i][q] = s2;
    }
#pragma unroll
  for (int dlt = 1; dlt < 16; dlt <<= 1)
#pragma unroll
    for (int i = 0; i < 4; ++i)
#pragma unroll
      for (int q = 0; q < 4; ++q) rowsum[i][q] += __shfl_xor(rowsum[i][q], dlt);
  if (cl == 0) {
#pragma unroll
    for (int i = 0; i < 4; ++i)
#pragma unroll
      for (int q = 0; q < 4; ++q)
        red[wr * 64 + i * 16 + kg * 4 + q][wc] = rowsum[i][q];
  }
  __syncthreads();
  if (tid < 128)
    atomicAdd(&fire_p[(size_t)(bc0 + tid) * 64 + r], red[tid][0] + red[tid][1]);
}

// ---------------- mask: exp + top-p over 64 rules ----------------
__global__ __launch_bounds__(256) void k_mask(const float* __restrict__ fire_p,
                                              float* __restrict__ nfs, float tau) {
  int w = threadIdx.x >> 6, lane = threadIdx.x & 63;
  int bc = blockIdx.x * 4 + w;
  size_t ix = (size_t)bc * 64 + lane;
  float f = expf(-0.001953125f * fire_p[ix]) + EPS_F;
  float tot = f;
#pragma unroll
  for (int d = 1; d < 64; d <<= 1) tot += __shfl_xor(tot, d);
  float nf = f / (tot + EPS_F);
  float v = nf;
#pragma unroll
  for (int k = 2; k <= 64; k <<= 1) {
#pragma unroll
    for (int j = 32; j > 0; j >>= 1) {
      if (j >= k) continue;
      float o = __shfl_xor(v, j);
      bool lower = (lane & j) == 0;
      bool desc = (lane & k) == 0;
      float mn = fminf(v, o), mx = fmaxf(v, o);
      v = (desc == lower) ? mx : mn;
    }
  }
  float cs = v;
#pragma unroll
  for (int d = 1; d < 64; d <<= 1) {
    float t = __shfl_up(cs, d);
    if (lane >= d) cs += t;
  }
  float err = cs - tau;
  if (err < 0.f) err = 1.0f;
  float mn = err;
#pragma unroll
  for (int d = 1; d < 64; d <<= 1) mn = fminf(mn, __shfl_xor(mn, d));
  unsigned long long ball = __ballot(err == mn);
  int idx = __ffsll(ball) - 1;
  float thresh = __shfl(v, idx);
  float keep = (nf >= thresh) ? nf : 0.0f;
  float tot2 = keep;
#pragma unroll
  for (int d = 1; d < 64; d <<= 1) tot2 += __shfl_xor(tot2, d);
  nfs[ix] = keep / (tot2 + EPS_F);
}

// ============ k_predg (m97 BK=64): pp_s[bc][p'] = sum_{r in slice} nfs*(x@G_r^T) + nfs.hv ============
// grid (2 ph, 32 bc, 8 slices), 256 thr, tile 128bc x 128p', BK=64, K=2048
__global__ __launch_bounds__(256) void k_predg(
    const unsigned short* __restrict__ xh, const unsigned short* __restrict__ G,
    const float* __restrict__ nfs, const float* __restrict__ hv,
    unsigned short* __restrict__ pp) {
  __shared__ unsigned short As[128 * 64];
  __shared__ unsigned short Bs[128 * 64];
  __shared__ float nl[128][8];
  const int tid = threadIdx.x, w = tid >> 6, lane = tid & 63;
  const int wr = w >> 1, wc = w & 1, cl = lane & 15, kg = lane >> 4;
  const int ph = blockIdx.x, bc0 = blockIdx.y * 128, sl = blockIdx.z;

  for (int e = tid; e < 1024; e += 256)
    nl[e >> 3][e & 7] = nfs[(size_t)(bc0 + (e >> 3)) * 64 + sl * 8 + (e & 7)];

  f32x4 acc[4][4];
#pragma unroll
  for (int i = 0; i < 4; ++i)
#pragma unroll
    for (int j = 0; j < 4; ++j) acc[i][j] = (f32x4){0.f, 0.f, 0.f, 0.f};

  _Float16 nlh[4];
  for (int t = 0; t < 32; ++t) {
    const int rr = t >> 2, kc = (t & 3) * 64;
    __syncthreads();
#pragma unroll
    for (int j = 0; j < 4; ++j) {
      int s = w * 4 + j;
      int ch = s * 64 + lane;
      int row = ch >> 3, c = ch & 7;
      gload16(xh + (size_t)(bc0 + row) * 256 + kc + ((c ^ (row & 7)) << 3),
              As + s * 512);
      gload16(G + (size_t)(sl * 8 + rr) * 65536 + (ph * 128 + row) * 256 + kc +
                  ((c ^ (row & 7)) << 3),
              Bs + s * 512);
    }
    __syncthreads();
    if ((t & 3) == 0) {
#pragma unroll
      for (int i = 0; i < 4; ++i)
        nlh[i] = (_Float16)nl[wr * 64 + i * 16 + cl][rr];
    }
#pragma unroll
    for (int kk = 0; kk < 2; ++kk) {
      half8 a[4], b[4];
      int g = kk * 4 + kg;
#pragma unroll
      for (int i = 0; i < 4; ++i) {
        int row = wr * 64 + i * 16 + cl;
        a[i] = *(const half8*)(As + row * 64 + ((g ^ (row & 7)) << 3));
        a[i] = a[i] * nlh[i];
      }
#pragma unroll
      for (int j = 0; j < 4; ++j) {
        int n = wc * 64 + j * 16 + cl;
        b[j] = *(const half8*)(Bs + n * 64 + ((g ^ (n & 7)) << 3));
      }
#pragma unroll
      for (int i = 0; i < 4; ++i)
#pragma unroll
        for (int j = 0; j < 4; ++j)
          acc[i][j] = __builtin_amdgcn_mfma_f32_16x16x32_f16(a[i], b[j], acc[i][j], 0, 0, 0);
    }
  }
  // epilogue: + sum_rr nfs*hv, store f16 partial
  float hvv[8][4];
#pragma unroll
  for (int j = 0; j < 4; ++j) {
    int col = ph * 128 + wc * 64 + j * 16 + cl;
#pragma unroll
    for (int rr = 0; rr < 8; ++rr)
      hvv[rr][j] = hv[(sl * 8 + rr) * 256 + col];
  }
  unsigned short* base = pp + (size_t)sl * 1048576;
#pragma unroll
  for (int i = 0; i < 4; ++i)
#pragma unroll
    for (int q = 0; q < 4; ++q) {
      int outrow = wr * 64 + i * 16 + kg * 4 + q;
      float nlv[8];
#pragma unroll
      for (int rr = 0; rr < 8; ++rr) nlv[rr] = nl[outrow][rr];
#pragma unroll
      for (int j = 0; j < 4; ++j) {
        float s = acc[i][j][q];
#pragma unroll
        for (int rr = 0; rr < 8; ++rr) s = fmaf(nlv[rr], hvv[rr][j], s);
        int col = ph * 128 + wc * 64 + j * 16 + cl;
        base[(size_t)(bc0 + outrow) * 256 + col] = f2h(s);
      }
    }
}

// ---------------- finalize output: out[b][p][c] = sum_s pp_s + bo ----------------
__global__ __launch_bounds__(256) void k_finalout(const unsigned short* __restrict__ pp,
                                                  const float* __restrict__ bo,
                                                  float* __restrict__ out) {
  __shared__ float bol[256];
  const int tid = threadIdx.x;
  bol[tid] = bo[tid];
  __syncthreads();
  const int row = tid & 31, pgrp = tid >> 5;
  const int bc = blockIdx.x * 32 + row;
  const int b = bc >> 9, c = bc & 511;
#pragma unroll
  for (int pc = 0; pc < 4; ++pc) {
    int p0 = pgrp * 32 + pc * 8;
    float s[8];
#pragma unroll
    for (int e = 0; e < 8; ++e) s[e] = 0.f;
#pragma unroll
    for (int sl = 0; sl < 8; ++sl) {
      ushort8 v = *(const ushort8*)(pp + (size_t)sl * 1048576 + (size_t)bc * 256 + p0);
#pragma unroll
      for (int e = 0; e < 8; ++e) s[e] += h2f(v[e]);
    }
#pragma unroll
    for (int e = 0; e < 8; ++e)
      out[(size_t)b * 131072 + (size_t)(p0 + e) * 512 + c] = s[e] + bol[p0 + e];
  }
}

// ---------------- finalize loss ----------------
__global__ __launch_bounds__(256) void k_final(
    const float* __restrict__ bq, const float* __restrict__ bk,
    const float* __restrict__ bv, const float* __restrict__ bo,
    const float* __restrict__ pbw, const float* __restrict__ pbk,
    const float* __restrict__ pbv, float* __restrict__ loss_out) {
  __shared__ float r[4][5];
  float swq = pbw[threadIdx.x];
  float sbk = 0.f, sbv = 0.f;
  for (int i = threadIdx.x; i < 4096; i += 256) {
    sbk += pbk[i];
    sbv += pbv[i];
  }
  for (int i = threadIdx.x; i < 16384; i += 256) {
    sbk += fabsf(bk[i]);
    sbv += fabsf(bv[i]);
  }
  float a = bq[threadIdx.x];
  float sbq = a * a;
  float b = bo[threadIdx.x];
  float sbo = b * b;
  int lane = threadIdx.x & 63, w = threadIdx.x >> 6;
#pragma unroll
  for (int d = 1; d < 64; d <<= 1) {
    swq += __shfl_xor(swq, d);
    sbk += __shfl_xor(sbk, d);
    sbv += __shfl_xor(sbv, d);
    sbq += __shfl_xor(sbq, d);
    sbo += __shfl_xor(sbo, d);
  }
  if (lane == 0) {
    r[w][0] = swq; r[w][1] = sbk; r[w][2] = sbv; r[w][3] = sbq; r[w][4] = sbo;
  }
  __syncthreads();
  if (threadIdx.x == 0) {
    float twq = r[0][0] + r[1][0] + r[2][0] + r[3][0];
    float tbk = r[0][1] + r[1][1] + r[2][1] + r[3][1];
    float tbv = r[0][2] + r[1][2] + r[2][2] + r[3][2];
    float tbq = r[0][3] + r[1][3] + r[2][3] + r[3][3];
    float tbo = r[0][4] + r[1][4] + r[2][4] + r[3][4];
    float loss = 0.01f * (sqrtf(twq) + sqrtf(tbq) + sqrtf(tbo)) +
                 0.001f * (tbk + tbv);
    *loss_out = loss;
  }
}

extern "C" void kernel_launch(void* const* d_in, const int* in_sizes, int n_in,
                              void* d_out, int out_size, void* d_ws, size_t ws_size,
                              hipStream_t stream) {
  const float* in    = (const float*)d_in[0];
  const float* Wq    = (const float*)d_in[1];
  const float* bq    = (const float*)d_in[2];
  const float* Wk    = (const float*)d_in[3];
  const float* bk    = (const float*)d_in[4];
  const float* Wv    = (const float*)d_in[5];
  const float* bv    = (const float*)d_in[6];
  const float* Wo    = (const float*)d_in[7];
  const float* bo    = (const float*)d_in[8];
  const float* sigma = (const float*)d_in[9];
  float* out = (float*)d_out;

  char* ws = (char*)d_ws;
  unsigned short* xh     = (unsigned short*)(ws);               // 2MB
  unsigned short* woh    = (unsigned short*)(ws + 2097152);     // 128KB
  float*          bdr    = (float*)(ws + 2228224);              // 64KB
  float*          nfs    = (float*)(ws + 2293760);              // 1MB
  float*          fire_p = (float*)(ws + 3342336);              // 1MB
  float*          pbk    = (float*)(ws + 4390912);              // 16KB
  float*          pbv    = (float*)(ws + 4407296);              // 16KB
  float*          pbw    = (float*)(ws + 4423680);              // 1KB
  float*          hv     = (float*)(ws + 4424704);              // 64KB
  unsigned short* wd     = (unsigned short*)(ws + 4718592);     // 8MB (dead after fire)
  unsigned short* wvT    = (unsigned short*)(ws + 13107200);    // 8MB (dead after gw)
  unsigned short* pp     = (unsigned short*)(ws + 4718592);     // 16MB overlay (wd+wvT)
  unsigned short* G      = (unsigned short*)(ws + 21495808);    // 8MB

  k_prep_x<<<dim3(16, 8, 8), 256, 0, stream>>>(in, xh);
  k_prep_w<<<4096, 256, 0, stream>>>(Wq, Wk, Wv, Wo, bq, bk, sigma,
                                     wd, woh, bdr, pbk, pbv);
  k_tv<<<dim3(8, 8, 64), 256, 0, stream>>>(Wv, wvT);
  k_wqwo<<<256, 256, 0, stream>>>(Wq, Wo, pbw);
  k_gw<<<dim3(2, 2, 64), 256, 0, stream>>>(woh, wvT, G);
  k_hv<<<64, 256, 0, stream>>>(woh, bv, hv);
  hipMemsetAsync(fire_p, 0, 1u << 20, stream);
  k_fire<<<dim3(2, 32, 64), 256, 0, stream>>>(xh, wd, bdr, fire_p);
  const float tau = (float)(0.9 * pow(1.0 / (64.0 + (double)EPS_F), 1.0 / 256.0));
  k_mask<<<1024, 256, 0, stream>>>(fire_p, nfs, tau);
  k_predg<<<dim3(2, 32, 8), 256, 0, stream>>>(xh, G, nfs, hv, pp);
  k_finalout<<<128, 256, 0, stream>>>(pp, bo, out);
  k_final<<<1, 256, 0, stream>>>(bq, bk, bv, bo, pbw, pbk, pbv, out + 1048576);
}

// Round 11
// 145.067 us; speedup vs baseline: 1.2527x; 1.2527x over previous
//
#include <hip/hip_runtime.h>
#include <math.h>

#define EPS_F 1.1754943508222875e-38f

typedef __attribute__((ext_vector_type(8))) _Float16 half8;
typedef __attribute__((ext_vector_type(4))) float f32x4;
typedef __attribute__((ext_vector_type(8))) unsigned short ushort8;

__device__ __forceinline__ unsigned short f2h(float f) {
  _Float16 h = (_Float16)f;
  return __builtin_bit_cast(unsigned short, h);
}
__device__ __forceinline__ float h2f(unsigned short u) {
  return (float)__builtin_bit_cast(_Float16, u);
}

// async global->LDS, 16B/lane; LDS dest = wave-uniform base (+ lane*16 by HW)
__device__ __forceinline__ void gload16(const void* g, void* l) {
  __builtin_amdgcn_global_load_lds(
      (const __attribute__((address_space(1))) void*)g,
      (__attribute__((address_space(3))) void*)l, 16, 0, 0);
}

// ---------------- prep: x transpose + f16 convert ----------------
__global__ __launch_bounds__(256) void k_prep_x(const float* __restrict__ in,
                                                unsigned short* __restrict__ x) {
  __shared__ float t[32][33];
  int c0 = blockIdx.x * 32, p0 = blockIdx.y * 32, b = blockIdx.z;
  int tx = threadIdx.x & 31, ty = threadIdx.x >> 5;
#pragma unroll
  for (int i = ty; i < 32; i += 8)
    t[i][tx] = in[(b * 256 + p0 + i) * 512 + c0 + tx];
  __syncthreads();
#pragma unroll
  for (int i = ty; i < 32; i += 8)
    x[(b * 512 + c0 + i) * 256 + p0 + tx] = f2h(t[tx][i]);
}

// ---------------- prep weights: wd=(Wq-Wk)/sigma (f16), woh, wqh, bdr, L1 partials ----------------
__global__ __launch_bounds__(256) void k_prep_w(
    const float* __restrict__ Wq, const float* __restrict__ Wk,
    const float* __restrict__ Wv, const float* __restrict__ Wo,
    const float* __restrict__ bq, const float* __restrict__ bk,
    const float* __restrict__ sigma,
    unsigned short* __restrict__ wd, unsigned short* __restrict__ woh,
    unsigned short* __restrict__ wqh, float* __restrict__ bdr,
    float* __restrict__ pbk, float* __restrict__ pbv) {
  __shared__ float r1[4], r2[4];
  int gid = blockIdx.x * 256 + threadIdx.x;
  int i4 = gid * 4;
  int rm = i4 >> 8, p = i4 & 255, m = rm & 255;
  const float4 wk = *(const float4*)(Wk + i4);
  const float4 wv = *(const float4*)(Wv + i4);
  const float4 wq = *(const float4*)(Wq + m * 256 + p);
  float rs = 1.0f / (sigma[rm] + EPS_F);
  ushort4 d;
  d.x = f2h((wq.x - wk.x) * rs); d.y = f2h((wq.y - wk.y) * rs);
  d.z = f2h((wq.z - wk.z) * rs); d.w = f2h((wq.w - wk.w) * rs);
  *(ushort4*)(wd + i4) = d;
  float ak = fabsf(wk.x) + fabsf(wk.y) + fabsf(wk.z) + fabsf(wk.w);
  float av = fabsf(wv.x) + fabsf(wv.y) + fabsf(wv.z) + fabsf(wv.w);
  if (p == 0) bdr[rm] = (bq[m] - bk[rm]) * rs;
  if (gid < 65536) {
    woh[gid] = f2h(Wo[gid]);
    ushort4 q4;
    q4.x = f2h(wq.x); q4.y = f2h(wq.y); q4.z = f2h(wq.z); q4.w = f2h(wq.w);
    *(ushort4*)(wqh + i4) = q4;
  }
  int lane = threadIdx.x & 63, w = threadIdx.x >> 6;
#pragma unroll
  for (int dlt = 1; dlt < 64; dlt <<= 1) {
    ak += __shfl_xor(ak, dlt);
    av += __shfl_xor(av, dlt);
  }
  if (lane == 0) { r1[w] = ak; r2[w] = av; }
  __syncthreads();
  if (threadIdx.x == 0) {
    pbk[blockIdx.x] = r1[0] + r1[1] + r1[2] + r1[3];
    pbv[blockIdx.x] = r2[0] + r2[1] + r2[2] + r2[3];
  }
}

// ---------------- transpose: z<64 -> wvT[r][p][m]; z==64 -> woT[m][p] ----------------
__global__ __launch_bounds__(256) void k_tv(const float* __restrict__ Wv,
                                            const float* __restrict__ Wo,
                                            unsigned short* __restrict__ wvT,
                                            unsigned short* __restrict__ woT) {
  __shared__ float t[32][33];
  int r = blockIdx.z;
  int tx = threadIdx.x & 31, ty = threadIdx.x >> 5;
  if (r < 64) {
    int p0 = blockIdx.x * 32, m0 = blockIdx.y * 32;
#pragma unroll
    for (int i = ty; i < 32; i += 8)
      t[i][tx] = Wv[(size_t)(r * 256 + m0 + i) * 256 + p0 + tx];
    __syncthreads();
#pragma unroll
    for (int i = ty; i < 32; i += 8)
      wvT[(size_t)r * 65536 + (p0 + i) * 256 + m0 + tx] = f2h(t[tx][i]);
  } else {
    int p0 = blockIdx.x * 32, m0 = blockIdx.y * 32;
#pragma unroll
    for (int i = ty; i < 32; i += 8)
      t[i][tx] = Wo[(p0 + i) * 256 + m0 + tx];
    __syncthreads();
#pragma unroll
    for (int i = ty; i < 32; i += 8)
      woT[(m0 + i) * 256 + p0 + tx] = f2h(t[tx][i]);
  }
}

// ---------------- loss: ||Wq@Wo - I||^2 via f16 MFMA, grid (2,2) ----------------
__global__ __launch_bounds__(256) void k_wqwo(const unsigned short* __restrict__ wqh,
                                              const unsigned short* __restrict__ woT,
                                              float* __restrict__ pbw) {
  __shared__ unsigned short As[128 * 64];
  __shared__ unsigned short Bs[128 * 64];
  __shared__ float red4[4];
  const int tid = threadIdx.x, w = tid >> 6, lane = tid & 63;
  const int wr = w >> 1, wc = w & 1, cl = lane & 15, kg = lane >> 4;
  const int bx = blockIdx.x, by = blockIdx.y;

  f32x4 acc[4][4];
#pragma unroll
  for (int i = 0; i < 4; ++i)
#pragma unroll
    for (int j = 0; j < 4; ++j) acc[i][j] = (f32x4){0.f, 0.f, 0.f, 0.f};

  for (int t = 0; t < 4; ++t) {
    const int kc = t * 64;
    __syncthreads();
#pragma unroll
    for (int j = 0; j < 4; ++j) {
      int s = w * 4 + j;
      int ch = s * 64 + lane;
      int row = ch >> 3, c = ch & 7;
      gload16(wqh + (by * 128 + row) * 256 + kc + ((c ^ (row & 7)) << 3),
              As + s * 512);
      gload16(woT + (bx * 128 + row) * 256 + kc + ((c ^ (row & 7)) << 3),
              Bs + s * 512);
    }
    __syncthreads();
#pragma unroll
    for (int kk = 0; kk < 2; ++kk) {
      half8 a[4], b[4];
      int g = kk * 4 + kg;
#pragma unroll
      for (int i = 0; i < 4; ++i) {
        int row = wr * 64 + i * 16 + cl;
        a[i] = *(const half8*)(As + row * 64 + ((g ^ (row & 7)) << 3));
      }
#pragma unroll
      for (int j = 0; j < 4; ++j) {
        int n = wc * 64 + j * 16 + cl;
        b[j] = *(const half8*)(Bs + n * 64 + ((g ^ (n & 7)) << 3));
      }
#pragma unroll
      for (int i = 0; i < 4; ++i)
#pragma unroll
        for (int j = 0; j < 4; ++j)
          acc[i][j] = __builtin_amdgcn_mfma_f32_16x16x32_f16(a[i], b[j], acc[i][j], 0, 0, 0);
    }
  }
  float s = 0.f;
#pragma unroll
  for (int i = 0; i < 4; ++i)
#pragma unroll
    for (int q = 0; q < 4; ++q) {
      int rg = by * 128 + wr * 64 + i * 16 + kg * 4 + q;
#pragma unroll
      for (int j = 0; j < 4; ++j) {
        int cg = bx * 128 + wc * 64 + j * 16 + cl;
        float dd = acc[i][j][q] - (rg == cg ? 1.0f : 0.0f);
        s += dd * dd;
      }
    }
#pragma unroll
  for (int d = 1; d < 64; d <<= 1) s += __shfl_xor(s, d);
  if (lane == 0) red4[w] = s;
  __syncthreads();
  if (tid == 0) pbw[by * 2 + bx] = red4[0] + red4[1] + red4[2] + red4[3];
}

// ============ k_gw: G_r[p'][p] = sum_m Wo[p'][m]*Wv_r[m][p] ============
__global__ __launch_bounds__(256) void k_gw(const unsigned short* __restrict__ woh,
                                            const unsigned short* __restrict__ wvT,
                                            unsigned short* __restrict__ G) {
  __shared__ unsigned short As[128 * 64];
  __shared__ unsigned short Bs[128 * 64];
  const int tid = threadIdx.x, w = tid >> 6, lane = tid & 63;
  const int wr = w >> 1, wc = w & 1, cl = lane & 15, kg = lane >> 4;
  const int pl = blockIdx.x, ph = blockIdx.y, r = blockIdx.z;

  f32x4 acc[4][4];
#pragma unroll
  for (int i = 0; i < 4; ++i)
#pragma unroll
    for (int j = 0; j < 4; ++j) acc[i][j] = (f32x4){0.f, 0.f, 0.f, 0.f};

  for (int t = 0; t < 4; ++t) {
    const int kc = t * 64;
    __syncthreads();
#pragma unroll
    for (int j = 0; j < 4; ++j) {
      int s = w * 4 + j;
      int ch = s * 64 + lane;
      int row = ch >> 3, c = ch & 7;
      gload16(woh + (ph * 128 + row) * 256 + kc + ((c ^ (row & 7)) << 3),
              As + s * 512);
      gload16(wvT + (size_t)r * 65536 + (pl * 128 + row) * 256 + kc +
                  ((c ^ (row & 7)) << 3),
              Bs + s * 512);
    }
    __syncthreads();
#pragma unroll
    for (int kk = 0; kk < 2; ++kk) {
      half8 a[4], b[4];
      int g = kk * 4 + kg;
#pragma unroll
      for (int i = 0; i < 4; ++i) {
        int row = wr * 64 + i * 16 + cl;
        a[i] = *(const half8*)(As + row * 64 + ((g ^ (row & 7)) << 3));
      }
#pragma unroll
      for (int j = 0; j < 4; ++j) {
        int n = wc * 64 + j * 16 + cl;
        b[j] = *(const half8*)(Bs + n * 64 + ((g ^ (n & 7)) << 3));
      }
#pragma unroll
      for (int i = 0; i < 4; ++i)
#pragma unroll
        for (int j = 0; j < 4; ++j)
          acc[i][j] = __builtin_amdgcn_mfma_f32_16x16x32_f16(a[i], b[j], acc[i][j], 0, 0, 0);
    }
  }
#pragma unroll
  for (int i = 0; i < 4; ++i)
#pragma unroll
    for (int q = 0; q < 4; ++q) {
      int pr = ph * 128 + wr * 64 + i * 16 + kg * 4 + q;
#pragma unroll
      for (int j = 0; j < 4; ++j) {
        int pc = pl * 128 + wc * 64 + j * 16 + cl;
        G[(size_t)r * 65536 + pr * 256 + pc] = f2h(acc[i][j][q]);
      }
    }
}

// ---------------- hv[r][p'] = sum_m Wo[p'][m]*bv[r][m] ----------------
__global__ __launch_bounds__(256) void k_hv(const unsigned short* __restrict__ woh,
                                            const float* __restrict__ bv,
                                            float* __restrict__ hv) {
  __shared__ float bvl[256];
  int r = blockIdx.x, t = threadIdx.x;
  bvl[t] = bv[r * 256 + t];
  __syncthreads();
  float s = 0.f;
#pragma unroll 8
  for (int c8 = 0; c8 < 32; ++c8) {
    ushort8 wv8 = *(const ushort8*)(woh + t * 256 + c8 * 8);
#pragma unroll
    for (int e = 0; e < 8; ++e) s = fmaf(h2f(wv8[e]), bvl[c8 * 8 + e], s);
  }
  hv[r * 256 + t] = s;
}

// ============ k_fire: full-m tile 128bc x 256m, wave 64x128, BK=64, no atomics ============
// grid 2048 linear (XCD-swizzled to (32bc, 64r)), 256 thr
__global__ __launch_bounds__(256, 2) void k_fire(
    const unsigned short* __restrict__ xh, const unsigned short* __restrict__ wd,
    const float* __restrict__ bdr, float* __restrict__ fire_p) {
  __shared__ unsigned short As[128 * 64];  // 16KB
  __shared__ unsigned short Bs[256 * 64];  // 32KB
  __shared__ float red[128][2];            // 1KB
  const int tid = threadIdx.x, w = tid >> 6, lane = tid & 63;
  const int wr = w >> 1, wc = w & 1, cl = lane & 15, kg = lane >> 4;
  const int wg = blockIdx.x;
  const int swz = (wg & 7) * 256 + (wg >> 3);  // XCD-contiguous: 8 r x 32 bc per XCD
  const int bc0 = (swz & 31) * 128, r = swz >> 5;

  float bdrv[8];
#pragma unroll
  for (int j = 0; j < 8; ++j)
    bdrv[j] = bdr[r * 256 + wc * 128 + j * 16 + cl];

  f32x4 acc[4][8];
#pragma unroll
  for (int i = 0; i < 4; ++i)
#pragma unroll
    for (int j = 0; j < 8; ++j) acc[i][j] = (f32x4){0.f, 0.f, 0.f, 0.f};

  for (int t = 0; t < 4; ++t) {
    const int kc = t * 64;
    __syncthreads();
#pragma unroll
    for (int j = 0; j < 4; ++j) {  // A: 128x64 = 16 slabs
      int s = w * 4 + j;
      int ch = s * 64 + lane;
      int row = ch >> 3, c = ch & 7;
      gload16(xh + (size_t)(bc0 + row) * 256 + kc + ((c ^ (row & 7)) << 3),
              As + s * 512);
    }
#pragma unroll
    for (int j = 0; j < 8; ++j) {  // B: 256x64 = 32 slabs
      int s = w * 8 + j;
      int ch = s * 64 + lane;
      int n = ch >> 3, c = ch & 7;
      gload16(wd + (size_t)r * 65536 + n * 256 + kc + ((c ^ (n & 7)) << 3),
              Bs + s * 512);
    }
    __syncthreads();
#pragma unroll
    for (int kk = 0; kk < 2; ++kk) {
      half8 a[4], b[8];
      int g = kk * 4 + kg;
#pragma unroll
      for (int i = 0; i < 4; ++i) {
        int row = wr * 64 + i * 16 + cl;
        a[i] = *(const half8*)(As + row * 64 + ((g ^ (row & 7)) << 3));
      }
#pragma unroll
      for (int j = 0; j < 8; ++j) {
        int n = wc * 128 + j * 16 + cl;
        b[j] = *(const half8*)(Bs + n * 64 + ((g ^ (n & 7)) << 3));
      }
#pragma unroll
      for (int i = 0; i < 4; ++i)
#pragma unroll
        for (int j = 0; j < 8; ++j)
          acc[i][j] = __builtin_amdgcn_mfma_f32_16x16x32_f16(a[i], b[j], acc[i][j], 0, 0, 0);
    }
  }
  // single epilogue: rowsum over this wave's 128 m-cols of (acc+bdr)^2
  float rowsum[4][4];
#pragma unroll
  for (int i = 0; i < 4; ++i)
#pragma unroll
    for (int q = 0; q < 4; ++q) {
      float s2 = 0.f;
#pragma unroll
      for (int j = 0; j < 8; ++j) {
        float t2 = acc[i][j][q] + bdrv[j];
        s2 += t2 * t2;
      }
      rowsum[i][q] = s2;
    }
#pragma unroll
  for (int dlt = 1; dlt < 16; dlt <<= 1)
#pragma unroll
    for (int i = 0; i < 4; ++i)
#pragma unroll
      for (int q = 0; q < 4; ++q) rowsum[i][q] += __shfl_xor(rowsum[i][q], dlt);
  if (cl == 0) {
#pragma unroll
    for (int i = 0; i < 4; ++i)
#pragma unroll
      for (int q = 0; q < 4; ++q)
        red[wr * 64 + i * 16 + kg * 4 + q][wc] = rowsum[i][q];
  }
  __syncthreads();
  if (tid < 128)
    fire_p[(size_t)(bc0 + tid) * 64 + r] = red[tid][0] + red[tid][1];
}

// ---------------- mask: exp + top-p over 64 rules ----------------
__global__ __launch_bounds__(256) void k_mask(const float* __restrict__ fire_p,
                                              float* __restrict__ nfs, float tau) {
  int w = threadIdx.x >> 6, lane = threadIdx.x & 63;
  int bc = blockIdx.x * 4 + w;
  size_t ix = (size_t)bc * 64 + lane;
  float f = expf(-0.001953125f * fire_p[ix]) + EPS_F;
  float tot = f;
#pragma unroll
  for (int d = 1; d < 64; d <<= 1) tot += __shfl_xor(tot, d);
  float nf = f / (tot + EPS_F);
  float v = nf;
#pragma unroll
  for (int k = 2; k <= 64; k <<= 1) {
#pragma unroll
    for (int j = 32; j > 0; j >>= 1) {
      if (j >= k) continue;
      float o = __shfl_xor(v, j);
      bool lower = (lane & j) == 0;
      bool desc = (lane & k) == 0;
      float mn = fminf(v, o), mx = fmaxf(v, o);
      v = (desc == lower) ? mx : mn;
    }
  }
  float cs = v;
#pragma unroll
  for (int d = 1; d < 64; d <<= 1) {
    float t = __shfl_up(cs, d);
    if (lane >= d) cs += t;
  }
  float err = cs - tau;
  if (err < 0.f) err = 1.0f;
  float mn = err;
#pragma unroll
  for (int d = 1; d < 64; d <<= 1) mn = fminf(mn, __shfl_xor(mn, d));
  unsigned long long ball = __ballot(err == mn);
  int idx = __ffsll(ball) - 1;
  float thresh = __shfl(v, idx);
  float keep = (nf >= thresh) ? nf : 0.0f;
  float tot2 = keep;
#pragma unroll
  for (int d = 1; d < 64; d <<= 1) tot2 += __shfl_xor(tot2, d);
  nfs[ix] = keep / (tot2 + EPS_F);
}

// ============ k_predg: pp_s[bc][p'] = sum_{r in slice} nfs*(x@G_r^T) + nfs.hv ============
// grid 512 linear (XCD-swizzled: each XCD owns one slice), 256 thr, BK=64
__global__ __launch_bounds__(256, 2) void k_predg(
    const unsigned short* __restrict__ xh, const unsigned short* __restrict__ G,
    const float* __restrict__ nfs, const float* __restrict__ hv,
    unsigned short* __restrict__ pp) {
  __shared__ unsigned short As[128 * 64];
  __shared__ unsigned short Bs[128 * 64];
  __shared__ float nl[128][8];
  const int tid = threadIdx.x, w = tid >> 6, lane = tid & 63;
  const int wr = w >> 1, wc = w & 1, cl = lane & 15, kg = lane >> 4;
  const int wg = blockIdx.x;
  const int swz = (wg & 7) * 64 + (wg >> 3);  // XCD k <-> slice k
  const int sl = swz >> 6, inner = swz & 63;
  const int bc0 = ((inner >> 1) & 31) * 128, ph = inner & 1;

  for (int e = tid; e < 1024; e += 256)
    nl[e >> 3][e & 7] = nfs[(size_t)(bc0 + (e >> 3)) * 64 + sl * 8 + (e & 7)];

  f32x4 acc[4][4];
#pragma unroll
  for (int i = 0; i < 4; ++i)
#pragma unroll
    for (int j = 0; j < 4; ++j) acc[i][j] = (f32x4){0.f, 0.f, 0.f, 0.f};

  _Float16 nlh[4];
  for (int t = 0; t < 32; ++t) {
    const int rr = t >> 2, kc = (t & 3) * 64;
    __syncthreads();
#pragma unroll
    for (int j = 0; j < 4; ++j) {
      int s = w * 4 + j;
      int ch = s * 64 + lane;
      int row = ch >> 3, c = ch & 7;
      gload16(xh + (size_t)(bc0 + row) * 256 + kc + ((c ^ (row & 7)) << 3),
              As + s * 512);
      gload16(G + (size_t)(sl * 8 + rr) * 65536 + (ph * 128 + row) * 256 + kc +
                  ((c ^ (row & 7)) << 3),
              Bs + s * 512);
    }
    __syncthreads();
    if ((t & 3) == 0) {
#pragma unroll
      for (int i = 0; i < 4; ++i)
        nlh[i] = (_Float16)nl[wr * 64 + i * 16 + cl][rr];
    }
#pragma unroll
    for (int kk = 0; kk < 2; ++kk) {
      half8 a[4], b[4];
      int g = kk * 4 + kg;
#pragma unroll
      for (int i = 0; i < 4; ++i) {
        int row = wr * 64 + i * 16 + cl;
        a[i] = *(const half8*)(As + row * 64 + ((g ^ (row & 7)) << 3));
        a[i] = a[i] * nlh[i];
      }
#pragma unroll
      for (int j = 0; j < 4; ++j) {
        int n = wc * 64 + j * 16 + cl;
        b[j] = *(const half8*)(Bs + n * 64 + ((g ^ (n & 7)) << 3));
      }
#pragma unroll
      for (int i = 0; i < 4; ++i)
#pragma unroll
        for (int j = 0; j < 4; ++j)
          acc[i][j] = __builtin_amdgcn_mfma_f32_16x16x32_f16(a[i], b[j], acc[i][j], 0, 0, 0);
    }
  }
  float hvv[8][4];
#pragma unroll
  for (int j = 0; j < 4; ++j) {
    int col = ph * 128 + wc * 64 + j * 16 + cl;
#pragma unroll
    for (int rr = 0; rr < 8; ++rr)
      hvv[rr][j] = hv[(sl * 8 + rr) * 256 + col];
  }
  unsigned short* base = pp + (size_t)sl * 1048576;
#pragma unroll
  for (int i = 0; i < 4; ++i)
#pragma unroll
    for (int q = 0; q < 4; ++q) {
      int outrow = wr * 64 + i * 16 + kg * 4 + q;
      float nlv[8];
#pragma unroll
      for (int rr = 0; rr < 8; ++rr) nlv[rr] = nl[outrow][rr];
#pragma unroll
      for (int j = 0; j < 4; ++j) {
        float s = acc[i][j][q];
#pragma unroll
        for (int rr = 0; rr < 8; ++rr) s = fmaf(nlv[rr], hvv[rr][j], s);
        int col = ph * 128 + wc * 64 + j * 16 + cl;
        base[(size_t)(bc0 + outrow) * 256 + col] = f2h(s);
      }
    }
}

// ---------------- finalize output: out[b][p][c] = sum_s pp_s + bo (LDS transpose) ----------------
__global__ __launch_bounds__(256) void k_finalout(const unsigned short* __restrict__ pp,
                                                  const float* __restrict__ bo,
                                                  float* __restrict__ out) {
  __shared__ float sacc[256][33];  // [p][bc_local], padded
  __shared__ float bol[256];
  const int tid = threadIdx.x;
  bol[tid] = bo[tid];
  const int bc0 = blockIdx.x * 32;
  const int b = bc0 >> 9, c0 = bc0 & 511;
  // phase 1: coalesced p-major reads, sum 8 slices
#pragma unroll
  for (int i = 0; i < 4; ++i) {
    int unit = tid + 256 * i;           // 0..1023 = 32 bc x 32 p-chunks
    int pch = unit & 31, lbc = unit >> 5;
    float s[8];
#pragma unroll
    for (int e = 0; e < 8; ++e) s[e] = 0.f;
#pragma unroll
    for (int sl = 0; sl < 8; ++sl) {
      ushort8 v = *(const ushort8*)(pp + (size_t)sl * 1048576 +
                                    (size_t)(bc0 + lbc) * 256 + pch * 8);
#pragma unroll
      for (int e = 0; e < 8; ++e) s[e] += h2f(v[e]);
    }
#pragma unroll
    for (int e = 0; e < 8; ++e) sacc[pch * 8 + e][lbc] = s[e];
  }
  __syncthreads();
  // phase 2: thread = one p row, write 32 consecutive c
  const int p = tid;
  float bov = bol[p];
  float* dst = out + (size_t)b * 131072 + (size_t)p * 512 + c0;
#pragma unroll
  for (int e0 = 0; e0 < 8; ++e0) {
    float4 v;
    v.x = sacc[p][e0 * 4 + 0] + bov;
    v.y = sacc[p][e0 * 4 + 1] + bov;
    v.z = sacc[p][e0 * 4 + 2] + bov;
    v.w = sacc[p][e0 * 4 + 3] + bov;
    *(float4*)(dst + e0 * 4) = v;
  }
}

// ---------------- finalize loss (1024 thr) ----------------
__global__ __launch_bounds__(1024) void k_final(
    const float* __restrict__ bq, const float* __restrict__ bk,
    const float* __restrict__ bv, const float* __restrict__ bo,
    const float* __restrict__ pbw, const float* __restrict__ pbk,
    const float* __restrict__ pbv, float* __restrict__ loss_out) {
  __shared__ float r[16][5];
  const int tid = threadIdx.x;
  float swq = (tid < 4) ? pbw[tid] : 0.f;
  float sbk = 0.f, sbv = 0.f;
  for (int i = tid; i < 4096; i += 1024) {
    sbk += pbk[i];
    sbv += pbv[i];
  }
  for (int i = tid; i < 16384; i += 1024) {
    sbk += fabsf(bk[i]);
    sbv += fabsf(bv[i]);
  }
  float sbq = 0.f, sbo = 0.f;
  if (tid < 256) {
    float a = bq[tid];
    sbq = a * a;
    float b = bo[tid];
    sbo = b * b;
  }
  int lane = tid & 63, w = tid >> 6;
#pragma unroll
  for (int d = 1; d < 64; d <<= 1) {
    swq += __shfl_xor(swq, d);
    sbk += __shfl_xor(sbk, d);
    sbv += __shfl_xor(sbv, d);
    sbq += __shfl_xor(sbq, d);
    sbo += __shfl_xor(sbo, d);
  }
  if (lane == 0) {
    r[w][0] = swq; r[w][1] = sbk; r[w][2] = sbv; r[w][3] = sbq; r[w][4] = sbo;
  }
  __syncthreads();
  if (tid == 0) {
    float t[5] = {0.f, 0.f, 0.f, 0.f, 0.f};
    for (int i = 0; i < 16; ++i)
      for (int j = 0; j < 5; ++j) t[j] += r[i][j];
    float loss = 0.01f * (sqrtf(t[0]) + sqrtf(t[3]) + sqrtf(t[4])) +
                 0.001f * (t[1] + t[2]);
    *loss_out = loss;
  }
}

extern "C" void kernel_launch(void* const* d_in, const int* in_sizes, int n_in,
                              void* d_out, int out_size, void* d_ws, size_t ws_size,
                              hipStream_t stream) {
  const float* in    = (const float*)d_in[0];
  const float* Wq    = (const float*)d_in[1];
  const float* bq    = (const float*)d_in[2];
  const float* Wk    = (const float*)d_in[3];
  const float* bk    = (const float*)d_in[4];
  const float* Wv    = (const float*)d_in[5];
  const float* bv    = (const float*)d_in[6];
  const float* Wo    = (const float*)d_in[7];
  const float* bo    = (const float*)d_in[8];
  const float* sigma = (const float*)d_in[9];
  float* out = (float*)d_out;

  char* ws = (char*)d_ws;
  unsigned short* xh     = (unsigned short*)(ws);               // 2MB
  unsigned short* woh    = (unsigned short*)(ws + 2097152);     // 128KB
  float*          bdr    = (float*)(ws + 2228224);              // 64KB
  float*          nfs    = (float*)(ws + 2293760);              // 1MB
  float*          fire_p = (float*)(ws + 3342336);              // 1MB
  float*          pbk    = (float*)(ws + 4390912);              // 16KB
  float*          pbv    = (float*)(ws + 4407296);              // 16KB
  float*          pbw    = (float*)(ws + 4423680);              // 1KB
  float*          hv     = (float*)(ws + 4424704);              // 64KB
  unsigned short* wd     = (unsigned short*)(ws + 4718592);     // 8MB (dead after fire)
  unsigned short* wvT    = (unsigned short*)(ws + 13107200);    // 8MB (dead after gw)
  unsigned short* pp     = (unsigned short*)(ws + 4718592);     // 8MB overlay (on wd)
  unsigned short* G      = (unsigned short*)(ws + 21495808);    // 8MB
  unsigned short* wqh    = (unsigned short*)(ws + 29884416);    // 128KB
  unsigned short* woT    = (unsigned short*)(ws + 30015488);    // 128KB

  k_prep_x<<<dim3(16, 8, 8), 256, 0, stream>>>(in, xh);
  k_prep_w<<<4096, 256, 0, stream>>>(Wq, Wk, Wv, Wo, bq, bk, sigma,
                                     wd, woh, wqh, bdr, pbk, pbv);
  k_tv<<<dim3(8, 8, 65), 256, 0, stream>>>(Wv, Wo, wvT, woT);
  k_wqwo<<<dim3(2, 2), 256, 0, stream>>>(wqh, woT, pbw);
  k_gw<<<dim3(2, 2, 64), 256, 0, stream>>>(woh, wvT, G);
  k_hv<<<64, 256, 0, stream>>>(woh, bv, hv);
  k_fire<<<2048, 256, 0, stream>>>(xh, wd, bdr, fire_p);
  const float tau = (float)(0.9 * pow(1.0 / (64.0 + (double)EPS_F), 1.0 / 256.0));
  k_mask<<<1024, 256, 0, stream>>>(fire_p, nfs, tau);
  k_predg<<<512, 256, 0, stream>>>(xh, G, nfs, hv, pp);
  k_finalout<<<128, 256, 0, stream>>>(pp, bo, out);
  k_final<<<1, 1024, 0, stream>>>(bq, bk, bv, bo, pbw, pbk, pbv, out + 1048576);
}

// Round 12
// 143.302 us; speedup vs baseline: 1.2681x; 1.0123x over previous
//
#include <hip/hip_runtime.h>
#include <math.h>

#define EPS_F 1.1754943508222875e-38f

typedef __attribute__((ext_vector_type(8))) _Float16 half8;
typedef __attribute__((ext_vector_type(4))) float f32x4;
typedef __attribute__((ext_vector_type(8))) unsigned short ushort8;

__device__ __forceinline__ unsigned short f2h(float f) {
  _Float16 h = (_Float16)f;
  return __builtin_bit_cast(unsigned short, h);
}
__device__ __forceinline__ float h2f(unsigned short u) {
  return (float)__builtin_bit_cast(_Float16, u);
}

// async global->LDS, 16B/lane; LDS dest = wave-uniform base (+ lane*16 by HW)
__device__ __forceinline__ void gload16(const void* g, void* l) {
  __builtin_amdgcn_global_load_lds(
      (const __attribute__((address_space(1))) void*)g,
      (__attribute__((address_space(3))) void*)l, 16, 0, 0);
}

// ---------------- prep: x transpose + f16 convert ----------------
__global__ __launch_bounds__(256) void k_prep_x(const float* __restrict__ in,
                                                unsigned short* __restrict__ x) {
  __shared__ float t[32][33];
  int c0 = blockIdx.x * 32, p0 = blockIdx.y * 32, b = blockIdx.z;
  int tx = threadIdx.x & 31, ty = threadIdx.x >> 5;
#pragma unroll
  for (int i = ty; i < 32; i += 8)
    t[i][tx] = in[(b * 256 + p0 + i) * 512 + c0 + tx];
  __syncthreads();
#pragma unroll
  for (int i = ty; i < 32; i += 8)
    x[(b * 512 + c0 + i) * 256 + p0 + tx] = f2h(t[tx][i]);
}

// ---------------- prep weights: wd=(Wq-Wk)/sigma (f16), woh, wqh, bdr, L1 partials ----------------
__global__ __launch_bounds__(256) void k_prep_w(
    const float* __restrict__ Wq, const float* __restrict__ Wk,
    const float* __restrict__ Wv, const float* __restrict__ Wo,
    const float* __restrict__ bq, const float* __restrict__ bk,
    const float* __restrict__ sigma,
    unsigned short* __restrict__ wd, unsigned short* __restrict__ woh,
    unsigned short* __restrict__ wqh, float* __restrict__ bdr,
    float* __restrict__ pbk, float* __restrict__ pbv) {
  __shared__ float r1[4], r2[4];
  int gid = blockIdx.x * 256 + threadIdx.x;
  int i4 = gid * 4;
  int rm = i4 >> 8, p = i4 & 255, m = rm & 255;
  const float4 wk = *(const float4*)(Wk + i4);
  const float4 wv = *(const float4*)(Wv + i4);
  const float4 wq = *(const float4*)(Wq + m * 256 + p);
  float rs = 1.0f / (sigma[rm] + EPS_F);
  ushort4 d;
  d.x = f2h((wq.x - wk.x) * rs); d.y = f2h((wq.y - wk.y) * rs);
  d.z = f2h((wq.z - wk.z) * rs); d.w = f2h((wq.w - wk.w) * rs);
  *(ushort4*)(wd + i4) = d;
  float ak = fabsf(wk.x) + fabsf(wk.y) + fabsf(wk.z) + fabsf(wk.w);
  float av = fabsf(wv.x) + fabsf(wv.y) + fabsf(wv.z) + fabsf(wv.w);
  if (p == 0) bdr[rm] = (bq[m] - bk[rm]) * rs;
  if (gid < 65536) {
    woh[gid] = f2h(Wo[gid]);
    ushort4 q4;
    q4.x = f2h(wq.x); q4.y = f2h(wq.y); q4.z = f2h(wq.z); q4.w = f2h(wq.w);
    *(ushort4*)(wqh + i4) = q4;
  }
  int lane = threadIdx.x & 63, w = threadIdx.x >> 6;
#pragma unroll
  for (int dlt = 1; dlt < 64; dlt <<= 1) {
    ak += __shfl_xor(ak, dlt);
    av += __shfl_xor(av, dlt);
  }
  if (lane == 0) { r1[w] = ak; r2[w] = av; }
  __syncthreads();
  if (threadIdx.x == 0) {
    pbk[blockIdx.x] = r1[0] + r1[1] + r1[2] + r1[3];
    pbv[blockIdx.x] = r2[0] + r2[1] + r2[2] + r2[3];
  }
}

// ---------------- transpose: z<64 -> wvT[r][p][m]; z==64 -> woT[m][p] ----------------
__global__ __launch_bounds__(256) void k_tv(const float* __restrict__ Wv,
                                            const float* __restrict__ Wo,
                                            unsigned short* __restrict__ wvT,
                                            unsigned short* __restrict__ woT) {
  __shared__ float t[32][33];
  int r = blockIdx.z;
  int tx = threadIdx.x & 31, ty = threadIdx.x >> 5;
  if (r < 64) {
    int p0 = blockIdx.x * 32, m0 = blockIdx.y * 32;
#pragma unroll
    for (int i = ty; i < 32; i += 8)
      t[i][tx] = Wv[(size_t)(r * 256 + m0 + i) * 256 + p0 + tx];
    __syncthreads();
#pragma unroll
    for (int i = ty; i < 32; i += 8)
      wvT[(size_t)r * 65536 + (p0 + i) * 256 + m0 + tx] = f2h(t[tx][i]);
  } else {
    int p0 = blockIdx.x * 32, m0 = blockIdx.y * 32;
#pragma unroll
    for (int i = ty; i < 32; i += 8)
      t[i][tx] = Wo[(p0 + i) * 256 + m0 + tx];
    __syncthreads();
#pragma unroll
    for (int i = ty; i < 32; i += 8)
      woT[(m0 + i) * 256 + p0 + tx] = f2h(t[tx][i]);
  }
}

// ---------------- loss: ||Wq@Wo - I||^2 via f16 MFMA, grid (2,2) ----------------
__global__ __launch_bounds__(256) void k_wqwo(const unsigned short* __restrict__ wqh,
                                              const unsigned short* __restrict__ woT,
                                              float* __restrict__ pbw) {
  __shared__ unsigned short As[128 * 64];
  __shared__ unsigned short Bs[128 * 64];
  __shared__ float red4[4];
  const int tid = threadIdx.x, w = tid >> 6, lane = tid & 63;
  const int wr = w >> 1, wc = w & 1, cl = lane & 15, kg = lane >> 4;
  const int bx = blockIdx.x, by = blockIdx.y;

  f32x4 acc[4][4];
#pragma unroll
  for (int i = 0; i < 4; ++i)
#pragma unroll
    for (int j = 0; j < 4; ++j) acc[i][j] = (f32x4){0.f, 0.f, 0.f, 0.f};

  for (int t = 0; t < 4; ++t) {
    const int kc = t * 64;
    __syncthreads();
#pragma unroll
    for (int j = 0; j < 4; ++j) {
      int s = w * 4 + j;
      int ch = s * 64 + lane;
      int row = ch >> 3, c = ch & 7;
      gload16(wqh + (by * 128 + row) * 256 + kc + ((c ^ (row & 7)) << 3),
              As + s * 512);
      gload16(woT + (bx * 128 + row) * 256 + kc + ((c ^ (row & 7)) << 3),
              Bs + s * 512);
    }
    __syncthreads();
#pragma unroll
    for (int kk = 0; kk < 2; ++kk) {
      half8 a[4], b[4];
      int g = kk * 4 + kg;
#pragma unroll
      for (int i = 0; i < 4; ++i) {
        int row = wr * 64 + i * 16 + cl;
        a[i] = *(const half8*)(As + row * 64 + ((g ^ (row & 7)) << 3));
      }
#pragma unroll
      for (int j = 0; j < 4; ++j) {
        int n = wc * 64 + j * 16 + cl;
        b[j] = *(const half8*)(Bs + n * 64 + ((g ^ (n & 7)) << 3));
      }
#pragma unroll
      for (int i = 0; i < 4; ++i)
#pragma unroll
        for (int j = 0; j < 4; ++j)
          acc[i][j] = __builtin_amdgcn_mfma_f32_16x16x32_f16(a[i], b[j], acc[i][j], 0, 0, 0);
    }
  }
  float s = 0.f;
#pragma unroll
  for (int i = 0; i < 4; ++i)
#pragma unroll
    for (int q = 0; q < 4; ++q) {
      int rg = by * 128 + wr * 64 + i * 16 + kg * 4 + q;
#pragma unroll
      for (int j = 0; j < 4; ++j) {
        int cg = bx * 128 + wc * 64 + j * 16 + cl;
        float dd = acc[i][j][q] - (rg == cg ? 1.0f : 0.0f);
        s += dd * dd;
      }
    }
#pragma unroll
  for (int d = 1; d < 64; d <<= 1) s += __shfl_xor(s, d);
  if (lane == 0) red4[w] = s;
  __syncthreads();
  if (tid == 0) pbw[by * 2 + bx] = red4[0] + red4[1] + red4[2] + red4[3];
}

// ============ k_gw: G_r[p'][p] = sum_m Wo[p'][m]*Wv_r[m][p] ============
__global__ __launch_bounds__(256) void k_gw(const unsigned short* __restrict__ woh,
                                            const unsigned short* __restrict__ wvT,
                                            unsigned short* __restrict__ G) {
  __shared__ unsigned short As[128 * 64];
  __shared__ unsigned short Bs[128 * 64];
  const int tid = threadIdx.x, w = tid >> 6, lane = tid & 63;
  const int wr = w >> 1, wc = w & 1, cl = lane & 15, kg = lane >> 4;
  const int pl = blockIdx.x, ph = blockIdx.y, r = blockIdx.z;

  f32x4 acc[4][4];
#pragma unroll
  for (int i = 0; i < 4; ++i)
#pragma unroll
    for (int j = 0; j < 4; ++j) acc[i][j] = (f32x4){0.f, 0.f, 0.f, 0.f};

  for (int t = 0; t < 4; ++t) {
    const int kc = t * 64;
    __syncthreads();
#pragma unroll
    for (int j = 0; j < 4; ++j) {
      int s = w * 4 + j;
      int ch = s * 64 + lane;
      int row = ch >> 3, c = ch & 7;
      gload16(woh + (ph * 128 + row) * 256 + kc + ((c ^ (row & 7)) << 3),
              As + s * 512);
      gload16(wvT + (size_t)r * 65536 + (pl * 128 + row) * 256 + kc +
                  ((c ^ (row & 7)) << 3),
              Bs + s * 512);
    }
    __syncthreads();
#pragma unroll
    for (int kk = 0; kk < 2; ++kk) {
      half8 a[4], b[4];
      int g = kk * 4 + kg;
#pragma unroll
      for (int i = 0; i < 4; ++i) {
        int row = wr * 64 + i * 16 + cl;
        a[i] = *(const half8*)(As + row * 64 + ((g ^ (row & 7)) << 3));
      }
#pragma unroll
      for (int j = 0; j < 4; ++j) {
        int n = wc * 64 + j * 16 + cl;
        b[j] = *(const half8*)(Bs + n * 64 + ((g ^ (n & 7)) << 3));
      }
#pragma unroll
      for (int i = 0; i < 4; ++i)
#pragma unroll
        for (int j = 0; j < 4; ++j)
          acc[i][j] = __builtin_amdgcn_mfma_f32_16x16x32_f16(a[i], b[j], acc[i][j], 0, 0, 0);
    }
  }
#pragma unroll
  for (int i = 0; i < 4; ++i)
#pragma unroll
    for (int q = 0; q < 4; ++q) {
      int pr = ph * 128 + wr * 64 + i * 16 + kg * 4 + q;
#pragma unroll
      for (int j = 0; j < 4; ++j) {
        int pc = pl * 128 + wc * 64 + j * 16 + cl;
        G[(size_t)r * 65536 + pr * 256 + pc] = f2h(acc[i][j][q]);
      }
    }
}

// ---------------- hv[r][p'] = sum_m Wo[p'][m]*bv[r][m] ----------------
__global__ __launch_bounds__(256) void k_hv(const unsigned short* __restrict__ woh,
                                            const float* __restrict__ bv,
                                            float* __restrict__ hv) {
  __shared__ float bvl[256];
  int r = blockIdx.x, t = threadIdx.x;
  bvl[t] = bv[r * 256 + t];
  __syncthreads();
  float s = 0.f;
#pragma unroll 8
  for (int c8 = 0; c8 < 32; ++c8) {
    ushort8 wv8 = *(const ushort8*)(woh + t * 256 + c8 * 8);
#pragma unroll
    for (int e = 0; e < 8; ++e) s = fmaf(h2f(wv8[e]), bvl[c8 * 8 + e], s);
  }
  hv[r * 256 + t] = s;
}

// ============ k_fire: full-m tile 128bc x 256m, wave 64x128, BK=64, no atomics ============
// grid 2048 linear (XCD-swizzled to (32bc, 64r)), 256 thr
__global__ __launch_bounds__(256, 2) void k_fire(
    const unsigned short* __restrict__ xh, const unsigned short* __restrict__ wd,
    const float* __restrict__ bdr, float* __restrict__ fire_p) {
  __shared__ unsigned short As[128 * 64];  // 16KB
  __shared__ unsigned short Bs[256 * 64];  // 32KB
  __shared__ float red[128][2];            // 1KB
  const int tid = threadIdx.x, w = tid >> 6, lane = tid & 63;
  const int wr = w >> 1, wc = w & 1, cl = lane & 15, kg = lane >> 4;
  const int wg = blockIdx.x;
  const int swz = (wg & 7) * 256 + (wg >> 3);  // XCD-contiguous: 8 r x 32 bc per XCD
  const int bc0 = (swz & 31) * 128, r = swz >> 5;

  float bdrv[8];
#pragma unroll
  for (int j = 0; j < 8; ++j)
    bdrv[j] = bdr[r * 256 + wc * 128 + j * 16 + cl];

  f32x4 acc[4][8];
#pragma unroll
  for (int i = 0; i < 4; ++i)
#pragma unroll
    for (int j = 0; j < 8; ++j) acc[i][j] = (f32x4){0.f, 0.f, 0.f, 0.f};

  for (int t = 0; t < 4; ++t) {
    const int kc = t * 64;
    __syncthreads();
#pragma unroll
    for (int j = 0; j < 4; ++j) {  // A: 128x64 = 16 slabs
      int s = w * 4 + j;
      int ch = s * 64 + lane;
      int row = ch >> 3, c = ch & 7;
      gload16(xh + (size_t)(bc0 + row) * 256 + kc + ((c ^ (row & 7)) << 3),
              As + s * 512);
    }
#pragma unroll
    for (int j = 0; j < 8; ++j) {  // B: 256x64 = 32 slabs
      int s = w * 8 + j;
      int ch = s * 64 + lane;
      int n = ch >> 3, c = ch & 7;
      gload16(wd + (size_t)r * 65536 + n * 256 + kc + ((c ^ (n & 7)) << 3),
              Bs + s * 512);
    }
    __syncthreads();
#pragma unroll
    for (int kk = 0; kk < 2; ++kk) {
      half8 a[4], b[8];
      int g = kk * 4 + kg;
#pragma unroll
      for (int i = 0; i < 4; ++i) {
        int row = wr * 64 + i * 16 + cl;
        a[i] = *(const half8*)(As + row * 64 + ((g ^ (row & 7)) << 3));
      }
#pragma unroll
      for (int j = 0; j < 8; ++j) {
        int n = wc * 128 + j * 16 + cl;
        b[j] = *(const half8*)(Bs + n * 64 + ((g ^ (n & 7)) << 3));
      }
#pragma unroll
      for (int i = 0; i < 4; ++i)
#pragma unroll
        for (int j = 0; j < 8; ++j)
          acc[i][j] = __builtin_amdgcn_mfma_f32_16x16x32_f16(a[i], b[j], acc[i][j], 0, 0, 0);
    }
  }
  // single epilogue: rowsum over this wave's 128 m-cols of (acc+bdr)^2
  float rowsum[4][4];
#pragma unroll
  for (int i = 0; i < 4; ++i)
#pragma unroll
    for (int q = 0; q < 4; ++q) {
      float s2 = 0.f;
#pragma unroll
      for (int j = 0; j < 8; ++j) {
        float t2 = acc[i][j][q] + bdrv[j];
        s2 += t2 * t2;
      }
      rowsum[i][q] = s2;
    }
#pragma unroll
  for (int dlt = 1; dlt < 16; dlt <<= 1)
#pragma unroll
    for (int i = 0; i < 4; ++i)
#pragma unroll
      for (int q = 0; q < 4; ++q) rowsum[i][q] += __shfl_xor(rowsum[i][q], dlt);
  if (cl == 0) {
#pragma unroll
    for (int i = 0; i < 4; ++i)
#pragma unroll
      for (int q = 0; q < 4; ++q)
        red[wr * 64 + i * 16 + kg * 4 + q][wc] = rowsum[i][q];
  }
  __syncthreads();
  if (tid < 128)
    fire_p[(size_t)(bc0 + tid) * 64 + r] = red[tid][0] + red[tid][1];
}

// ---------------- mask: exp + top-p over 64 rules ----------------
__global__ __launch_bounds__(256) void k_mask(const float* __restrict__ fire_p,
                                              float* __restrict__ nfs, float tau) {
  int w = threadIdx.x >> 6, lane = threadIdx.x & 63;
  int bc = blockIdx.x * 4 + w;
  size_t ix = (size_t)bc * 64 + lane;
  float f = expf(-0.001953125f * fire_p[ix]) + EPS_F;
  float tot = f;
#pragma unroll
  for (int d = 1; d < 64; d <<= 1) tot += __shfl_xor(tot, d);
  float nf = f / (tot + EPS_F);
  float v = nf;
#pragma unroll
  for (int k = 2; k <= 64; k <<= 1) {
#pragma unroll
    for (int j = 32; j > 0; j >>= 1) {
      if (j >= k) continue;
      float o = __shfl_xor(v, j);
      bool lower = (lane & j) == 0;
      bool desc = (lane & k) == 0;
      float mn = fminf(v, o), mx = fmaxf(v, o);
      v = (desc == lower) ? mx : mn;
    }
  }
  float cs = v;
#pragma unroll
  for (int d = 1; d < 64; d <<= 1) {
    float t = __shfl_up(cs, d);
    if (lane >= d) cs += t;
  }
  float err = cs - tau;
  if (err < 0.f) err = 1.0f;
  float mn = err;
#pragma unroll
  for (int d = 1; d < 64; d <<= 1) mn = fminf(mn, __shfl_xor(mn, d));
  unsigned long long ball = __ballot(err == mn);
  int idx = __ffsll(ball) - 1;
  float thresh = __shfl(v, idx);
  float keep = (nf >= thresh) ? nf : 0.0f;
  float tot2 = keep;
#pragma unroll
  for (int d = 1; d < 64; d <<= 1) tot2 += __shfl_xor(tot2, d);
  nfs[ix] = keep / (tot2 + EPS_F);
}

// ============ k_predg: pp_s[bc][p'] = sum_{r in slice} nfs*(x@G_r^T) + nfs.hv ============
// grid 512 linear (XCD-swizzled), 512 thr (8 waves of 32bc x 64p'), BK=64
__global__ __launch_bounds__(512, 4) void k_predg(
    const unsigned short* __restrict__ xh, const unsigned short* __restrict__ G,
    const float* __restrict__ nfs, const float* __restrict__ hv,
    unsigned short* __restrict__ pp) {
  __shared__ unsigned short As[128 * 64];  // 16KB
  __shared__ unsigned short Bs[128 * 64];  // 16KB
  __shared__ float nl[128][9];             // 4.5KB padded (9 coprime 32)
  const int tid = threadIdx.x, w = tid >> 6, lane = tid & 63;
  const int wr = w >> 1, wc = w & 1, cl = lane & 15, kg = lane >> 4;
  const int wg = blockIdx.x;
  const int swz = (wg & 7) * 64 + (wg >> 3);  // XCD k <-> slice k
  const int sl = swz >> 6, inner = swz & 63;
  const int bc0 = ((inner >> 1) & 31) * 128, ph = inner & 1;

  for (int e = tid; e < 1024; e += 512)
    nl[e >> 3][e & 7] = nfs[(size_t)(bc0 + (e >> 3)) * 64 + sl * 8 + (e & 7)];

  f32x4 acc[2][4];
#pragma unroll
  for (int i = 0; i < 2; ++i)
#pragma unroll
    for (int j = 0; j < 4; ++j) acc[i][j] = (f32x4){0.f, 0.f, 0.f, 0.f};

  _Float16 nlh[2];
  for (int t = 0; t < 32; ++t) {
    const int rr = t >> 2, kc = (t & 3) * 64;
    __syncthreads();
#pragma unroll
    for (int j = 0; j < 2; ++j) {
      int s = w * 2 + j;
      int ch = s * 64 + lane;
      int row = ch >> 3, c = ch & 7;
      gload16(xh + (size_t)(bc0 + row) * 256 + kc + ((c ^ (row & 7)) << 3),
              As + s * 512);
      gload16(G + (size_t)(sl * 8 + rr) * 65536 + (ph * 128 + row) * 256 + kc +
                  ((c ^ (row & 7)) << 3),
              Bs + s * 512);
    }
    __syncthreads();
    if ((t & 3) == 0) {
#pragma unroll
      for (int i = 0; i < 2; ++i)
        nlh[i] = (_Float16)nl[wr * 32 + i * 16 + cl][rr];
    }
#pragma unroll
    for (int kk = 0; kk < 2; ++kk) {
      half8 a[2], b[4];
      int g = kk * 4 + kg;
#pragma unroll
      for (int i = 0; i < 2; ++i) {
        int row = wr * 32 + i * 16 + cl;
        a[i] = *(const half8*)(As + row * 64 + ((g ^ (row & 7)) << 3));
        a[i] = a[i] * nlh[i];
      }
#pragma unroll
      for (int j = 0; j < 4; ++j) {
        int n = wc * 64 + j * 16 + cl;
        b[j] = *(const half8*)(Bs + n * 64 + ((g ^ (n & 7)) << 3));
      }
#pragma unroll
      for (int i = 0; i < 2; ++i)
#pragma unroll
        for (int j = 0; j < 4; ++j)
          acc[i][j] = __builtin_amdgcn_mfma_f32_16x16x32_f16(a[i], b[j], acc[i][j], 0, 0, 0);
    }
  }
  float hvv[8][4];
#pragma unroll
  for (int j = 0; j < 4; ++j) {
    int col = ph * 128 + wc * 64 + j * 16 + cl;
#pragma unroll
    for (int rr = 0; rr < 8; ++rr)
      hvv[rr][j] = hv[(sl * 8 + rr) * 256 + col];
  }
  unsigned short* base = pp + (size_t)sl * 1048576;
#pragma unroll
  for (int i = 0; i < 2; ++i)
#pragma unroll
    for (int q = 0; q < 4; ++q) {
      int outrow = wr * 32 + i * 16 + kg * 4 + q;
      float nlv[8];
#pragma unroll
      for (int rr = 0; rr < 8; ++rr) nlv[rr] = nl[outrow][rr];
#pragma unroll
      for (int j = 0; j < 4; ++j) {
        float s = acc[i][j][q];
#pragma unroll
        for (int rr = 0; rr < 8; ++rr) s = fmaf(nlv[rr], hvv[rr][j], s);
        int col = ph * 128 + wc * 64 + j * 16 + cl;
        base[(size_t)(bc0 + outrow) * 256 + col] = f2h(s);
      }
    }
}

// ---------------- finalize output: out[b][p][c] = sum_s pp_s + bo (LDS transpose) ----------------
__global__ __launch_bounds__(256) void k_finalout(const unsigned short* __restrict__ pp,
                                                  const float* __restrict__ bo,
                                                  float* __restrict__ out) {
  __shared__ float sacc[256][33];  // [p][bc_local], padded
  __shared__ float bol[256];
  const int tid = threadIdx.x;
  bol[tid] = bo[tid];
  const int bc0 = blockIdx.x * 32;
  const int b = bc0 >> 9, c0 = bc0 & 511;
#pragma unroll
  for (int i = 0; i < 4; ++i) {
    int unit = tid + 256 * i;
    int pch = unit & 31, lbc = unit >> 5;
    float s[8];
#pragma unroll
    for (int e = 0; e < 8; ++e) s[e] = 0.f;
#pragma unroll
    for (int sl = 0; sl < 8; ++sl) {
      ushort8 v = *(const ushort8*)(pp + (size_t)sl * 1048576 +
                                    (size_t)(bc0 + lbc) * 256 + pch * 8);
#pragma unroll
      for (int e = 0; e < 8; ++e) s[e] += h2f(v[e]);
    }
#pragma unroll
    for (int e = 0; e < 8; ++e) sacc[pch * 8 + e][lbc] = s[e];
  }
  __syncthreads();
  const int p = tid;
  float bov = bol[p];
  float* dst = out + (size_t)b * 131072 + (size_t)p * 512 + c0;
#pragma unroll
  for (int e0 = 0; e0 < 8; ++e0) {
    float4 v;
    v.x = sacc[p][e0 * 4 + 0] + bov;
    v.y = sacc[p][e0 * 4 + 1] + bov;
    v.z = sacc[p][e0 * 4 + 2] + bov;
    v.w = sacc[p][e0 * 4 + 3] + bov;
    *(float4*)(dst + e0 * 4) = v;
  }
}

// ---------------- finalize loss (1024 thr) ----------------
__global__ __launch_bounds__(1024) void k_final(
    const float* __restrict__ bq, const float* __restrict__ bk,
    const float* __restrict__ bv, const float* __restrict__ bo,
    const float* __restrict__ pbw, const float* __restrict__ pbk,
    const float* __restrict__ pbv, float* __restrict__ loss_out) {
  __shared__ float r[16][5];
  const int tid = threadIdx.x;
  float swq = (tid < 4) ? pbw[tid] : 0.f;
  float sbk = 0.f, sbv = 0.f;
  for (int i = tid; i < 4096; i += 1024) {
    sbk += pbk[i];
    sbv += pbv[i];
  }
  for (int i = tid; i < 16384; i += 1024) {
    sbk += fabsf(bk[i]);
    sbv += fabsf(bv[i]);
  }
  float sbq = 0.f, sbo = 0.f;
  if (tid < 256) {
    float a = bq[tid];
    sbq = a * a;
    float b = bo[tid];
    sbo = b * b;
  }
  int lane = tid & 63, w = tid >> 6;
#pragma unroll
  for (int d = 1; d < 64; d <<= 1) {
    swq += __shfl_xor(swq, d);
    sbk += __shfl_xor(sbk, d);
    sbv += __shfl_xor(sbv, d);
    sbq += __shfl_xor(sbq, d);
    sbo += __shfl_xor(sbo, d);
  }
  if (lane == 0) {
    r[w][0] = swq; r[w][1] = sbk; r[w][2] = sbv; r[w][3] = sbq; r[w][4] = sbo;
  }
  __syncthreads();
  if (tid == 0) {
    float t[5] = {0.f, 0.f, 0.f, 0.f, 0.f};
    for (int i = 0; i < 16; ++i)
      for (int j = 0; j < 5; ++j) t[j] += r[i][j];
    float loss = 0.01f * (sqrtf(t[0]) + sqrtf(t[3]) + sqrtf(t[4])) +
                 0.001f * (t[1] + t[2]);
    *loss_out = loss;
  }
}

extern "C" void kernel_launch(void* const* d_in, const int* in_sizes, int n_in,
                              void* d_out, int out_size, void* d_ws, size_t ws_size,
                              hipStream_t stream) {
  const float* in    = (const float*)d_in[0];
  const float* Wq    = (const float*)d_in[1];
  const float* bq    = (const float*)d_in[2];
  const float* Wk    = (const float*)d_in[3];
  const float* bk    = (const float*)d_in[4];
  const float* Wv    = (const float*)d_in[5];
  const float* bv    = (const float*)d_in[6];
  const float* Wo    = (const float*)d_in[7];
  const float* bo    = (const float*)d_in[8];
  const float* sigma = (const float*)d_in[9];
  float* out = (float*)d_out;

  char* ws = (char*)d_ws;
  unsigned short* xh     = (unsigned short*)(ws);               // 2MB
  unsigned short* woh    = (unsigned short*)(ws + 2097152);     // 128KB
  float*          bdr    = (float*)(ws + 2228224);              // 64KB
  float*          nfs    = (float*)(ws + 2293760);              // 1MB
  float*          fire_p = (float*)(ws + 3342336);              // 1MB
  float*          pbk    = (float*)(ws + 4390912);              // 16KB
  float*          pbv    = (float*)(ws + 4407296);              // 16KB
  float*          pbw    = (float*)(ws + 4423680);              // 1KB
  float*          hv     = (float*)(ws + 4424704);              // 64KB
  unsigned short* wd     = (unsigned short*)(ws + 4718592);     // 8MB (dead after fire)
  unsigned short* wvT    = (unsigned short*)(ws + 13107200);    // 8MB (dead after gw)
  unsigned short* pp     = (unsigned short*)(ws + 4718592);     // 8MB overlay (on wd)
  unsigned short* G      = (unsigned short*)(ws + 21495808);    // 8MB
  unsigned short* wqh    = (unsigned short*)(ws + 29884416);    // 128KB
  unsigned short* woT    = (unsigned short*)(ws + 30015488);    // 128KB

  k_prep_x<<<dim3(16, 8, 8), 256, 0, stream>>>(in, xh);
  k_prep_w<<<4096, 256, 0, stream>>>(Wq, Wk, Wv, Wo, bq, bk, sigma,
                                     wd, woh, wqh, bdr, pbk, pbv);
  k_tv<<<dim3(8, 8, 65), 256, 0, stream>>>(Wv, Wo, wvT, woT);
  k_wqwo<<<dim3(2, 2), 256, 0, stream>>>(wqh, woT, pbw);
  k_gw<<<dim3(2, 2, 64), 256, 0, stream>>>(woh, wvT, G);
  k_hv<<<64, 256, 0, stream>>>(woh, bv, hv);
  k_fire<<<2048, 256, 0, stream>>>(xh, wd, bdr, fire_p);
  const float tau = (float)(0.9 * pow(1.0 / (64.0 + (double)EPS_F), 1.0 / 256.0));
  k_mask<<<1024, 256, 0, stream>>>(fire_p, nfs, tau);
  k_predg<<<512, 512, 0, stream>>>(xh, G, nfs, hv, pp);
  k_finalout<<<128, 256, 0, stream>>>(pp, bo, out);
  k_final<<<1, 1024, 0, stream>>>(bq, bk, bv, bo, pbw, pbk, pbv, out + 1048576);
}